// Round 2
// baseline (425.650 us; speedup 1.0000x reference)
//
#include <hip/hip_runtime.h>
#include <math.h>

// ============================================================================
// GetImportantStruct — round 4: dispatch-count attack. 12 -> 7 dispatches:
//   k_prep   : fused zeroing + LDS-atomic bincounts + 3 exclusive scans (1 blk)
//   k_score  : wave-per-node dot/scale/low/rem (unchanged)
//   k_pass1  : candidate edges + br-drop scatter (unchanged)
//   k_pass2  : edge-keep sums + dropcnt | brmask sums | br-edge sums (E|N2|EB)
//   k_scanABC: 3-block scan of all block-sum arrays -> totals[0..2]
//   k_pass3  : edge scan-write + edge_num_plus | remap scan-write
//   k_pass45 : br-edge scan-write | inform row copy | feature rows + br_batch
// Copies are float4 (16B/lane). Theory: prior 423us was dominated by
// per-dispatch overhead + serialization, not bytes (~315MB = ~50us floor).
// ============================================================================

// ---------------- fused prep: counts, counts2, scans, zeroing (1 block) -----
__device__ __forceinline__ int scan512_excl_val(int v, int* s){
  int t = threadIdx.x;
  s[t] = v; __syncthreads();
  for (int off = 1; off < 512; off <<= 1){
    int add = (t >= off) ? s[t - off] : 0;
    __syncthreads();
    s[t] += add;
    __syncthreads();
  }
  int r = s[t] - v;
  __syncthreads();
  return r;
}

__global__ void __launch_bounds__(512) k_prep(
    const int* __restrict__ batch, int N,
    const int* __restrict__ br_batch, int N2,
    const int* __restrict__ edge_num, int G,
    int* __restrict__ counts, int* __restrict__ counts2,
    int* __restrict__ node_off, int* __restrict__ node_off2,
    int* __restrict__ e_off,
    int* __restrict__ dropcnt, int* __restrict__ brmask){
  __shared__ int c1[512], c2[512], s[512];
  int t = threadIdx.x;
  c1[t] = 0; c2[t] = 0;
  __syncthreads();
  for (int i = t; i < N;  i += 512) atomicAdd(&c1[batch[i]], 1);
  for (int i = t; i < N2; i += 512) atomicAdd(&c2[br_batch[i]], 1);
  // zero the scatter targets while counting is in flight
  for (int i = t; i < G;  i += 512) dropcnt[i] = 0;
  for (int i = t; i < N2; i += 512) brmask[i] = 0;
  __syncthreads();
  int v1 = (t < G) ? c1[t] : 0;
  int v2 = (t < G) ? c2[t] : 0;
  int v3 = (t < G) ? edge_num[t] : 0;
  int o1 = scan512_excl_val(v1, s);
  int o2 = scan512_excl_val(v2, s);
  int o3 = scan512_excl_val(v3, s);
  if (t < G){
    counts[t]  = v1;  node_off[t]  = o1;
    counts2[t] = v2;  node_off2[t] = o2;
    e_off[t]   = o3;
  }
}

// ---------------- score / x_out / low / rem-init: one WAVE per node ---------
// Row (C floats) held in registers, butterfly shfl reduction, single global
// pass. sigmoid(m)<0.5  <=>  dot<0.
__global__ void __launch_bounds__(256) k_score(
    const float* __restrict__ x, const float* __restrict__ W,
    const int* __restrict__ batch, const int* __restrict__ counts,
    const int* __restrict__ node_off,
    float* __restrict__ out_x, int* __restrict__ low, int* __restrict__ rem,
    int C, int N){
  int wave = (blockIdx.x * blockDim.x + threadIdx.x) >> 6;
  int lane = threadIdx.x & 63;
  if (wave >= N) return;
  const float4* x4 = (const float4*)(x + (size_t)wave * C);
  const float4* W4 = (const float4*)W;
  const int nv = C >> 2;
  float4 vals[8];
  float acc = 0.f;
  int m = 0;
  for (int k = lane; k < nv; k += 64){
    float4 a = x4[k]; float4 w = W4[k];
    acc += a.x*w.x + a.y*w.y + a.z*w.z + a.w*w.w;
    if (m < 8) vals[m] = a;
    m++;
  }
  #pragma unroll
  for (int d = 1; d < 64; d <<= 1) acc += __shfl_xor(acc, d, 64);
  float scale = 2.0f / (1.0f + expf(-acc / (float)C));   // 2*sigmoid(mean)
  if (lane == 0){
    int g    = batch[wave];
    int last = node_off[g] + counts[g] - 1;
    low[wave] = (acc < 0.0f) && (wave != last) ? 1 : 0;
    rem[wave] = -1;
  }
  float4* o4 = (float4*)(out_x + (size_t)wave * C);
  m = 0;
  for (int k = lane; k < nv; k += 64){
    float4 a = (m < 8) ? vals[m] : x4[k];
    m++;
    a.x *= scale; a.y *= scale; a.z *= scale; a.w *= scale;
    o4[k] = a;
  }
}

// ---------------- edge -> graph lookup --------------------------------------
__device__ __forceinline__ int find_graph(const int* __restrict__ e_off, int G, int e){
  int lo = 0, hi = G - 1;            // largest g with e_off[g] <= e
  while (lo < hi){
    int mid = (lo + hi + 1) >> 1;
    if (e_off[mid] <= e) lo = mid; else hi = mid - 1;
  }
  return lo;
}

// ---------------- pass1: candidate edges (E) + br drop scatter (N) ----------
__global__ void k_pass1(const int* __restrict__ ei, const int* __restrict__ e_off,
                        const int* __restrict__ node_off, const int* __restrict__ node_off2,
                        const int* __restrict__ counts, const int* __restrict__ batch,
                        const int* __restrict__ low, const int* __restrict__ br_com_num,
                        int* __restrict__ rem, int* __restrict__ brmask,
                        int E, int N, int G){
  int e = blockIdx.x*blockDim.x + threadIdx.x;
  if (e < N && low[e]){                       // br-drop scatter for node e
    int g = batch[e];
    int d = e - node_off[g] + br_com_num[g] + node_off2[g];
    brmask[d] = 1;                            // 1 = dropped (mask pre-zeroed)
  }
  if (e >= E) return;
  int g  = find_graph(e_off, G, e);
  if (e - e_off[g] < 1) return;               // local_pos >= 1
  int dst  = ei[E + e];
  int last = node_off[g] + counts[g] - 1;
  if (dst != last) return;
  int src = ei[e];
  if (!low[src]) return;
  if (batch[src] != g) return;
  atomicMax(&rem[src], e);
}

// ---------------- pass2: blocksums for E (edges), N2 (br nodes), EB (br edges)
__global__ void k_pass2(const int* __restrict__ ei, const int* __restrict__ rem,
                        const int* __restrict__ e_off, const int* __restrict__ brmask,
                        const int* __restrict__ bi,
                        int* __restrict__ dropcnt,
                        int* __restrict__ bsumsA, int* __restrict__ bsumsB,
                        int* __restrict__ bsumsC,
                        int E, int N2, int EB, int G, int nbE, int nbN2){
  __shared__ int s[256];
  int b = blockIdx.x, t = threadIdx.x;
  int v = 0;
  if (b < nbE){
    int e = b*256 + t;
    if (e < E){
      v = (rem[ei[e]] != e) ? 1 : 0;
      if (!v){ int g = find_graph(e_off, G, e); atomicAdd(&dropcnt[g], 1); }
    }
  } else if (b < nbE + nbN2){
    int j = (b - nbE)*256 + t;
    v = (j < N2) ? (brmask[j] == 0) : 0;
  } else {
    int e = (b - nbE - nbN2)*256 + t;
    if (e < EB)
      v = (brmask[bi[e]] == 0 && brmask[bi[EB + e]] == 0) ? 1 : 0;
  }
  s[t] = v; __syncthreads();
  for (int off = 128; off > 0; off >>= 1){
    if (t < off) s[t] += s[t + off];
    __syncthreads();
  }
  if (t == 0){
    if (b < nbE)            bsumsA[b] = s[0];
    else if (b < nbE + nbN2) bsumsB[b - nbE] = s[0];
    else                     bsumsC[b - nbE - nbN2] = s[0];
  }
}

// ---------------- scan of all three block-sum arrays (3 blocks) -------------
__device__ void scan_bsums_dev(int* __restrict__ bsums, int nb, int* __restrict__ total){
  __shared__ int s[1024];
  int t = threadIdx.x;
  int v = (t < nb) ? bsums[t] : 0;
  s[t] = v; __syncthreads();
  for (int off = 1; off < 1024; off <<= 1){
    int add = (t >= off) ? s[t - off] : 0;
    __syncthreads();
    s[t] += add;
    __syncthreads();
  }
  if (t < nb)      bsums[t] = s[t] - v;
  if (t == nb - 1) *total   = s[t];
}

__global__ void k_scanABC(int* __restrict__ bsumsA, int nbA,
                          int* __restrict__ bsumsB, int nbB,
                          int* __restrict__ bsumsC, int nbC,
                          int* __restrict__ totals){
  if      (blockIdx.x == 0) scan_bsums_dev(bsumsA, nbA, &totals[0]);
  else if (blockIdx.x == 1) scan_bsums_dev(bsumsB, nbB, &totals[1]);
  else                      scan_bsums_dev(bsumsC, nbC, &totals[2]);
}

__device__ __forceinline__ int excl_scan256(int v, int* s){
  int t = threadIdx.x;
  s[t] = v; __syncthreads();
  for (int off = 1; off < 256; off <<= 1){
    int add = (t >= off) ? s[t - off] : 0;
    __syncthreads();
    s[t] += add;
    __syncthreads();
  }
  return s[t] - v;
}

// ---------------- pass3: edge scan-write + edgenum (E) | node scan-write (N2)
__global__ void k_pass3(const int* __restrict__ ei, const int* __restrict__ rem,
                        const int* __restrict__ bsumsA, const int* __restrict__ bsumsB,
                        const int* __restrict__ totals,
                        const int* __restrict__ edge_num, const int* __restrict__ dropcnt,
                        const int* __restrict__ brmask,
                        int* __restrict__ edge_pos, int* __restrict__ remap,
                        float* __restrict__ out, long long base0,
                        int E, int N2, int G, int DE, int nbE){
  __shared__ int s[256];
  int b = blockIdx.x, t = threadIdx.x;
  if (b < nbE){
    int e = b*256 + t;
    int keep = 0, src = 0, dst = 0;
    if (e < E){ src = ei[e]; dst = ei[E + e]; keep = (rem[src] != e) ? 1 : 0; }
    int excl = excl_scan256(keep, s);
    long long ek = totals[0];
    if (e < E){
      if (keep){
        int p = bsumsA[b] + excl;
        edge_pos[e] = p;
        out[base0 + p]      = (float)src;
        out[base0 + ek + p] = (float)dst;
      } else edge_pos[e] = -1;
    }
    if (b == 0){
      long long off3 = base0 + 2*ek + ek*(long long)DE;
      for (int g = t; g < G; g += 256)
        out[off3 + g] = (float)(edge_num[g] - dropcnt[g]);
    }
  } else {
    int j = (b - nbE)*256 + t;
    int keep = (j < N2) ? (brmask[j] == 0) : 0;
    int excl = excl_scan256(keep, s);
    if (j < N2) remap[j] = keep ? (bsumsB[b - nbE] + excl) : -1;
  }
}

// ---------------- pass45: br-edge scan-write (EB) | inform rows (E) |
//                  br_feature rows + br_batch (N2)
__global__ void __launch_bounds__(256) k_pass45(
    const int* __restrict__ bi, const int* __restrict__ remap,
    const int* __restrict__ bsumsC, const int* __restrict__ totals,
    const float* __restrict__ inform, const int* __restrict__ edge_pos,
    const float* __restrict__ brf, const int* __restrict__ brb,
    float* __restrict__ out, long long base0,
    int G, int DE, int C, int EB, int E, int N2,
    int nbB, int nbE8){
  int b = blockIdx.x, t = threadIdx.x;
  long long ek = totals[0];
  if (b < nbB){
    // ---- br-edge compacted index write ----
    __shared__ int s[256];
    long long nk = totals[1], kc = totals[2];
    long long off4 = base0 + 2*ek + ek*(long long)DE + G;      // br_feature_p
    int e = b*256 + t;
    int r = -1, c = -1, keep = 0;
    if (e < EB){
      r = remap[bi[e]];
      c = remap[bi[EB + e]];
      keep = (r >= 0 && c >= 0) ? 1 : 0;
    }
    int excl = excl_scan256(keep, s);
    if (keep){
      long long off5 = off4 + nk*(long long)C;                 // br_index_p
      int p = bsumsC[b] + excl;
      out[off5 + p]      = (float)r;
      out[off5 + kc + p] = (float)c;
    }
  } else if (b < nbB + nbE8){
    // ---- inform copy: 8 rows/block, 32 lanes x float4 per 512B row ----
    int e = (b - nbB)*8 + (t >> 5);
    if (e >= E) return;
    int p = edge_pos[e];
    if (p < 0) return;
    long long off2 = base0 + 2*ek;
    int lane = t & 31;
    const float4* in4 = (const float4*)(inform + (size_t)e * DE);
    float4*       o4  = (float4*)(out + off2 + (long long)p * DE);
    for (int j = lane; j < (DE >> 2); j += 32) o4[j] = in4[j];
  } else {
    // ---- br_feature rows: 2 rows/block, 128 lanes x float4 per 2KB row ----
    long long nk = totals[1], kc = totals[2];
    long long off4 = base0 + 2*ek + ek*(long long)DE + G;
    int j = (b - nbB - nbE8)*2 + (t >> 7);
    if (j >= N2) return;
    int p = remap[j];
    if (p < 0) return;
    int lane = t & 127;
    const float4* in4 = (const float4*)(brf + (size_t)j * C);
    float4*       o4  = (float4*)(out + off4 + (long long)p * C);
    for (int k = lane; k < (C >> 2); k += 128) o4[k] = in4[k];
    if (lane == 0){
      long long off6 = off4 + nk*(long long)C + 2*kc;          // br_batch_p
      out[off6 + p] = (float)brb[j];
    }
  }
}

// ============================================================================
extern "C" void kernel_launch(void* const* d_in, const int* in_sizes, int n_in,
                              void* d_out, int out_size, void* d_ws, size_t ws_size,
                              hipStream_t stream){
  const float* x           = (const float*)d_in[0];
  const int*   edge_index  = (const int*)  d_in[1];
  const int*   edge_num    = (const int*)  d_in[2];
  const float* edge_inform = (const float*)d_in[3];
  const int*   batch       = (const int*)  d_in[4];
  const float* br_feature  = (const float*)d_in[5];
  const int*   br_index    = (const int*)  d_in[6];
  const int*   br_batch    = (const int*)  d_in[7];
  const int*   br_com_num  = (const int*)  d_in[8];
  const float* W           = (const float*)d_in[9];
  float* out = (float*)d_out;

  const int C  = in_sizes[9];          // W is (1, C)
  const int N  = in_sizes[4];          // batch
  const int G  = in_sizes[2];          // edge_num
  const int E  = in_sizes[1] / 2;      // edge_index (2, E)
  const int DE = in_sizes[3] / E;      // edge_inform (E, DE)
  const int N2 = in_sizes[7];          // br_batch
  const int EB = in_sizes[6] / 2;      // br_index (2, EB)

  // ---- workspace layout (ints) ----
  int* ws        = (int*)d_ws;
  int* counts    = ws;                 // G
  int* counts2   = counts    + G;      // G
  int* dropcnt   = counts2   + G;      // G   (zeroed by k_prep)
  int* brmask    = dropcnt   + G;      // N2  (zeroed by k_prep)
  int* node_off  = brmask    + N2;     // G
  int* node_off2 = node_off  + G;      // G
  int* e_off     = node_off2 + G;      // G
  int* totals    = e_off     + G;      // 8: [0]=e_kept [1]=n_kept [2]=kc
  int* low       = totals    + 8;      // N
  int* rem       = low       + N;      // N
  int* remap     = rem       + N;      // N2
  int* edge_pos  = remap     + N2;     // E
  int* bsumsA    = edge_pos  + E;      // 1024
  int* bsumsB    = bsumsA    + 1024;   // 1024
  int* bsumsC    = bsumsB    + 1024;   // 1024

  const long long base0 = (long long)N * C;   // end of x_out chunk

  const int nbN2 = (N2 + 255) / 256;
  const int nbE  = (E  + 255) / 256;   // <= 1024
  const int nbB  = (EB + 255) / 256;   // <= 1024
  const int nbE8 = (E + 7) / 8;

  k_prep<<<1, 512, 0, stream>>>(batch, N, br_batch, N2, edge_num, G,
                                counts, counts2, node_off, node_off2, e_off,
                                dropcnt, brmask);

  k_score<<<(N * 64 + 255) / 256, 256, 0, stream>>>(x, W, batch, counts, node_off,
                                                    out, low, rem, C, N);

  k_pass1<<<(max(E, N) + 255) / 256, 256, 0, stream>>>(
      edge_index, e_off, node_off, node_off2, counts, batch, low, br_com_num,
      rem, brmask, E, N, G);

  k_pass2<<<nbE + nbN2 + nbB, 256, 0, stream>>>(edge_index, rem, e_off, brmask,
                                                br_index, dropcnt,
                                                bsumsA, bsumsB, bsumsC,
                                                E, N2, EB, G, nbE, nbN2);

  k_scanABC<<<3, 1024, 0, stream>>>(bsumsA, nbE, bsumsB, nbN2, bsumsC, nbB,
                                    totals);

  k_pass3<<<nbE + nbN2, 256, 0, stream>>>(edge_index, rem, bsumsA, bsumsB, totals,
                                          edge_num, dropcnt, brmask,
                                          edge_pos, remap, out, base0,
                                          E, N2, G, DE, nbE);

  k_pass45<<<nbB + nbE8 + (N2 + 1) / 2, 256, 0, stream>>>(
      br_index, remap, bsumsC, totals, edge_inform, edge_pos,
      br_feature, br_batch, out, base0,
      G, DE, C, EB, E, N2, nbB, nbE8);
}

// Round 4
// 359.159 us; speedup vs baseline: 1.1851x; 1.1851x over previous
//
#include <hip/hip_runtime.h>
#include <math.h>

// ============================================================================
// GetImportantStruct — round 5 (resubmit; infra failure last round):
//  (1) k_score had a runtime-indexed register array (vals[m], runtime trip
//      count) -> scratch spill (rule #20). Now: wave-uniform fast path for
//      C==512 with two NAMED float4 registers; generic 2-pass fallback.
//  (2) round-4's single-block k_prep serially read 256KB + wrote 128KB on one
//      CU (~50-70us). Split back: parallel k_count (LDS hists, 64 blocks,
//      also zeroes brmask/dropcnt) + tiny 1-block k_scan.
// Pipeline: memset(2KB) + k_count + k_scan + k_score + k_pass1 + k_pass2 +
//           k_scanABC + k_pass3 + k_pass45  (9 dispatches)
// ============================================================================

// ---------------- parallel counting + scatter-target zeroing ----------------
__global__ void __launch_bounds__(512) k_count(
    const int* __restrict__ batch, int N,
    const int* __restrict__ br_batch, int N2,
    int* __restrict__ counts, int* __restrict__ counts2,
    int* __restrict__ dropcnt, int* __restrict__ brmask, int G){
  __shared__ int h1[512], h2[512];
  int t = threadIdx.x;
  h1[t] = 0; h2[t] = 0;
  __syncthreads();
  int gid    = blockIdx.x*blockDim.x + t;
  int stride = gridDim.x*blockDim.x;
  for (int i = gid; i < N;  i += stride) atomicAdd(&h1[batch[i]], 1);
  for (int i = gid; i < N2; i += stride) atomicAdd(&h2[br_batch[i]], 1);
  for (int i = gid; i < N2; i += stride) brmask[i] = 0;
  if (gid < G) dropcnt[gid] = 0;
  __syncthreads();
  if (t < G){
    if (h1[t]) atomicAdd(&counts[t],  h1[t]);
    if (h2[t]) atomicAdd(&counts2[t], h2[t]);
  }
}

// ---------------- G-length exclusive scans (single block, 512 threads) ------
__device__ __forceinline__ int scan512_excl_val(int v, int* s){
  int t = threadIdx.x;
  s[t] = v; __syncthreads();
  for (int off = 1; off < 512; off <<= 1){
    int add = (t >= off) ? s[t - off] : 0;
    __syncthreads();
    s[t] += add;
    __syncthreads();
  }
  int r = s[t] - v;
  __syncthreads();
  return r;
}

__global__ void __launch_bounds__(512) k_scan(
    const int* __restrict__ counts, const int* __restrict__ counts2,
    const int* __restrict__ edge_num, int G,
    int* __restrict__ node_off, int* __restrict__ node_off2,
    int* __restrict__ e_off){
  __shared__ int s[512];
  int t = threadIdx.x;
  int v1 = (t < G) ? counts[t]   : 0;
  int v2 = (t < G) ? counts2[t]  : 0;
  int v3 = (t < G) ? edge_num[t] : 0;
  int o1 = scan512_excl_val(v1, s);
  int o2 = scan512_excl_val(v2, s);
  int o3 = scan512_excl_val(v3, s);
  if (t < G){ node_off[t] = o1; node_off2[t] = o2; e_off[t] = o3; }
}

// ---------------- score / x_out / low / rem-init: one WAVE per node ---------
// sigmoid(m)<0.5 <=> dot<0. Fast path (C==512): exactly 2 float4 per lane,
// NAMED registers (no runtime-indexed array -> no scratch). Generic path:
// two-pass (re-read x), no caching.
__global__ void __launch_bounds__(256) k_score(
    const float* __restrict__ x, const float* __restrict__ W,
    const int* __restrict__ batch, const int* __restrict__ counts,
    const int* __restrict__ node_off,
    float* __restrict__ out_x, int* __restrict__ low, int* __restrict__ rem,
    int C, int N){
  int wave = (blockIdx.x * blockDim.x + threadIdx.x) >> 6;
  int lane = threadIdx.x & 63;
  if (wave >= N) return;
  const float4* x4 = (const float4*)(x + (size_t)wave * C);
  const float4* W4 = (const float4*)W;
  const int nv = C >> 2;
  float acc = 0.f;
  float4 a0, a1;
  const bool fast = (nv == 128);          // wave-uniform branch
  if (fast){
    float4 w0 = W4[lane], w1 = W4[lane + 64];
    a0 = x4[lane]; a1 = x4[lane + 64];
    acc = a0.x*w0.x + a0.y*w0.y + a0.z*w0.z + a0.w*w0.w
        + a1.x*w1.x + a1.y*w1.y + a1.z*w1.z + a1.w*w1.w;
  } else {
    for (int k = lane; k < nv; k += 64){
      float4 a = x4[k]; float4 w = W4[k];
      acc += a.x*w.x + a.y*w.y + a.z*w.z + a.w*w.w;
    }
  }
  #pragma unroll
  for (int d = 1; d < 64; d <<= 1) acc += __shfl_xor(acc, d, 64);
  float scale = 2.0f / (1.0f + expf(-acc / (float)C));   // 2*sigmoid(mean)
  if (lane == 0){
    int g    = batch[wave];
    int last = node_off[g] + counts[g] - 1;
    low[wave] = (acc < 0.0f) && (wave != last) ? 1 : 0;
    rem[wave] = -1;
  }
  float4* o4 = (float4*)(out_x + (size_t)wave * C);
  if (fast){
    a0.x *= scale; a0.y *= scale; a0.z *= scale; a0.w *= scale;
    a1.x *= scale; a1.y *= scale; a1.z *= scale; a1.w *= scale;
    o4[lane]      = a0;
    o4[lane + 64] = a1;
  } else {
    for (int k = lane; k < nv; k += 64){
      float4 a = x4[k];
      a.x *= scale; a.y *= scale; a.z *= scale; a.w *= scale;
      o4[k] = a;
    }
  }
}

// ---------------- edge -> graph lookup --------------------------------------
__device__ __forceinline__ int find_graph(const int* __restrict__ e_off, int G, int e){
  int lo = 0, hi = G - 1;            // largest g with e_off[g] <= e
  while (lo < hi){
    int mid = (lo + hi + 1) >> 1;
    if (e_off[mid] <= e) lo = mid; else hi = mid - 1;
  }
  return lo;
}

// ---------------- pass1: candidate edges (E) + br drop scatter (N) ----------
__global__ void k_pass1(const int* __restrict__ ei, const int* __restrict__ e_off,
                        const int* __restrict__ node_off, const int* __restrict__ node_off2,
                        const int* __restrict__ counts, const int* __restrict__ batch,
                        const int* __restrict__ low, const int* __restrict__ br_com_num,
                        int* __restrict__ rem, int* __restrict__ brmask,
                        int E, int N, int G){
  int e = blockIdx.x*blockDim.x + threadIdx.x;
  if (e < N && low[e]){                       // br-drop scatter for node e
    int g = batch[e];
    int d = e - node_off[g] + br_com_num[g] + node_off2[g];
    brmask[d] = 1;                            // 1 = dropped (mask pre-zeroed)
  }
  if (e >= E) return;
  int g  = find_graph(e_off, G, e);
  if (e - e_off[g] < 1) return;               // local_pos >= 1
  int dst  = ei[E + e];
  int last = node_off[g] + counts[g] - 1;
  if (dst != last) return;
  int src = ei[e];
  if (!low[src]) return;
  if (batch[src] != g) return;
  atomicMax(&rem[src], e);
}

// ---------------- pass2: blocksums for E (edges), N2 (br nodes), EB (br edges)
__global__ void k_pass2(const int* __restrict__ ei, const int* __restrict__ rem,
                        const int* __restrict__ e_off, const int* __restrict__ brmask,
                        const int* __restrict__ bi,
                        int* __restrict__ dropcnt,
                        int* __restrict__ bsumsA, int* __restrict__ bsumsB,
                        int* __restrict__ bsumsC,
                        int E, int N2, int EB, int G, int nbE, int nbN2){
  __shared__ int s[256];
  int b = blockIdx.x, t = threadIdx.x;
  int v = 0;
  if (b < nbE){
    int e = b*256 + t;
    if (e < E){
      v = (rem[ei[e]] != e) ? 1 : 0;
      if (!v){ int g = find_graph(e_off, G, e); atomicAdd(&dropcnt[g], 1); }
    }
  } else if (b < nbE + nbN2){
    int j = (b - nbE)*256 + t;
    v = (j < N2) ? (brmask[j] == 0) : 0;
  } else {
    int e = (b - nbE - nbN2)*256 + t;
    if (e < EB)
      v = (brmask[bi[e]] == 0 && brmask[bi[EB + e]] == 0) ? 1 : 0;
  }
  s[t] = v; __syncthreads();
  for (int off = 128; off > 0; off >>= 1){
    if (t < off) s[t] += s[t + off];
    __syncthreads();
  }
  if (t == 0){
    if (b < nbE)             bsumsA[b] = s[0];
    else if (b < nbE + nbN2) bsumsB[b - nbE] = s[0];
    else                     bsumsC[b - nbE - nbN2] = s[0];
  }
}

// ---------------- scan of all three block-sum arrays (3 blocks) -------------
__device__ void scan_bsums_dev(int* __restrict__ bsums, int nb, int* __restrict__ total){
  __shared__ int s[1024];
  int t = threadIdx.x;
  int v = (t < nb) ? bsums[t] : 0;
  s[t] = v; __syncthreads();
  for (int off = 1; off < 1024; off <<= 1){
    int add = (t >= off) ? s[t - off] : 0;
    __syncthreads();
    s[t] += add;
    __syncthreads();
  }
  if (t < nb)      bsums[t] = s[t] - v;
  if (t == nb - 1) *total   = s[t];
}

__global__ void k_scanABC(int* __restrict__ bsumsA, int nbA,
                          int* __restrict__ bsumsB, int nbB,
                          int* __restrict__ bsumsC, int nbC,
                          int* __restrict__ totals){
  if      (blockIdx.x == 0) scan_bsums_dev(bsumsA, nbA, &totals[0]);
  else if (blockIdx.x == 1) scan_bsums_dev(bsumsB, nbB, &totals[1]);
  else                      scan_bsums_dev(bsumsC, nbC, &totals[2]);
}

__device__ __forceinline__ int excl_scan256(int v, int* s){
  int t = threadIdx.x;
  s[t] = v; __syncthreads();
  for (int off = 1; off < 256; off <<= 1){
    int add = (t >= off) ? s[t - off] : 0;
    __syncthreads();
    s[t] += add;
    __syncthreads();
  }
  return s[t] - v;
}

// ---------------- pass3: edge scan-write + edgenum (E) | node scan-write (N2)
__global__ void k_pass3(const int* __restrict__ ei, const int* __restrict__ rem,
                        const int* __restrict__ bsumsA, const int* __restrict__ bsumsB,
                        const int* __restrict__ totals,
                        const int* __restrict__ edge_num, const int* __restrict__ dropcnt,
                        const int* __restrict__ brmask,
                        int* __restrict__ edge_pos, int* __restrict__ remap,
                        float* __restrict__ out, long long base0,
                        int E, int N2, int G, int DE, int nbE){
  __shared__ int s[256];
  int b = blockIdx.x, t = threadIdx.x;
  if (b < nbE){
    int e = b*256 + t;
    int keep = 0, src = 0, dst = 0;
    if (e < E){ src = ei[e]; dst = ei[E + e]; keep = (rem[src] != e) ? 1 : 0; }
    int excl = excl_scan256(keep, s);
    long long ek = totals[0];
    if (e < E){
      if (keep){
        int p = bsumsA[b] + excl;
        edge_pos[e] = p;
        out[base0 + p]      = (float)src;
        out[base0 + ek + p] = (float)dst;
      } else edge_pos[e] = -1;
    }
    if (b == 0){
      long long off3 = base0 + 2*ek + ek*(long long)DE;
      for (int g = t; g < G; g += 256)
        out[off3 + g] = (float)(edge_num[g] - dropcnt[g]);
    }
  } else {
    int j = (b - nbE)*256 + t;
    int keep = (j < N2) ? (brmask[j] == 0) : 0;
    int excl = excl_scan256(keep, s);
    if (j < N2) remap[j] = keep ? (bsumsB[b - nbE] + excl) : -1;
  }
}

// ---------------- pass45: br-edge scan-write (EB) | inform rows (E) |
//                  br_feature rows + br_batch (N2)
__global__ void __launch_bounds__(256) k_pass45(
    const int* __restrict__ bi, const int* __restrict__ remap,
    const int* __restrict__ bsumsC, const int* __restrict__ totals,
    const float* __restrict__ inform, const int* __restrict__ edge_pos,
    const float* __restrict__ brf, const int* __restrict__ brb,
    float* __restrict__ out, long long base0,
    int G, int DE, int C, int EB, int E, int N2,
    int nbB, int nbE8){
  int b = blockIdx.x, t = threadIdx.x;
  long long ek = totals[0];
  if (b < nbB){
    // ---- br-edge compacted index write ----
    __shared__ int s[256];
    long long nk = totals[1], kc = totals[2];
    long long off4 = base0 + 2*ek + ek*(long long)DE + G;      // br_feature_p
    int e = b*256 + t;
    int r = -1, c = -1, keep = 0;
    if (e < EB){
      r = remap[bi[e]];
      c = remap[bi[EB + e]];
      keep = (r >= 0 && c >= 0) ? 1 : 0;
    }
    int excl = excl_scan256(keep, s);
    if (keep){
      long long off5 = off4 + nk*(long long)C;                 // br_index_p
      int p = bsumsC[b] + excl;
      out[off5 + p]      = (float)r;
      out[off5 + kc + p] = (float)c;
    }
  } else if (b < nbB + nbE8){
    // ---- inform copy: 8 rows/block, 32 lanes x float4 per 512B row ----
    int e = (b - nbB)*8 + (t >> 5);
    if (e >= E) return;
    int p = edge_pos[e];
    if (p < 0) return;
    long long off2 = base0 + 2*ek;
    int lane = t & 31;
    const float4* in4 = (const float4*)(inform + (size_t)e * DE);
    float4*       o4  = (float4*)(out + off2 + (long long)p * DE);
    for (int j = lane; j < (DE >> 2); j += 32) o4[j] = in4[j];
  } else {
    // ---- br_feature rows: 2 rows/block, 128 lanes x float4 per 2KB row ----
    long long nk = totals[1], kc = totals[2];
    long long off4 = base0 + 2*ek + ek*(long long)DE + G;
    int j = (b - nbB - nbE8)*2 + (t >> 7);
    if (j >= N2) return;
    int p = remap[j];
    if (p < 0) return;
    int lane = t & 127;
    const float4* in4 = (const float4*)(brf + (size_t)j * C);
    float4*       o4  = (float4*)(out + off4 + (long long)p * C);
    for (int k = lane; k < (C >> 2); k += 128) o4[k] = in4[k];
    if (lane == 0){
      long long off6 = off4 + nk*(long long)C + 2*kc;          // br_batch_p
      out[off6 + p] = (float)brb[j];
    }
  }
}

// ============================================================================
extern "C" void kernel_launch(void* const* d_in, const int* in_sizes, int n_in,
                              void* d_out, int out_size, void* d_ws, size_t ws_size,
                              hipStream_t stream){
  const float* x           = (const float*)d_in[0];
  const int*   edge_index  = (const int*)  d_in[1];
  const int*   edge_num    = (const int*)  d_in[2];
  const float* edge_inform = (const float*)d_in[3];
  const int*   batch       = (const int*)  d_in[4];
  const float* br_feature  = (const float*)d_in[5];
  const int*   br_index    = (const int*)  d_in[6];
  const int*   br_batch    = (const int*)  d_in[7];
  const int*   br_com_num  = (const int*)  d_in[8];
  const float* W           = (const float*)d_in[9];
  float* out = (float*)d_out;

  const int C  = in_sizes[9];          // W is (1, C)
  const int N  = in_sizes[4];          // batch
  const int G  = in_sizes[2];          // edge_num
  const int E  = in_sizes[1] / 2;      // edge_index (2, E)
  const int DE = in_sizes[3] / E;      // edge_inform (E, DE)
  const int N2 = in_sizes[7];          // br_batch
  const int EB = in_sizes[6] / 2;      // br_index (2, EB)

  // ---- workspace layout (ints) ----
  int* ws        = (int*)d_ws;
  int* counts    = ws;                 // G   (zeroed by memset)
  int* counts2   = counts    + G;      // G   (zeroed by memset)
  int* dropcnt   = counts2   + G;      // G   (zeroed by k_count)
  int* brmask    = dropcnt   + G;      // N2  (zeroed by k_count)
  int* node_off  = brmask    + N2;     // G
  int* node_off2 = node_off  + G;      // G
  int* e_off     = node_off2 + G;      // G
  int* totals    = e_off     + G;      // 8: [0]=e_kept [1]=n_kept [2]=kc
  int* low       = totals    + 8;      // N
  int* rem       = low       + N;      // N
  int* remap     = rem       + N;      // N2
  int* edge_pos  = remap     + N2;     // E
  int* bsumsA    = edge_pos  + E;      // 1024
  int* bsumsB    = bsumsA    + 1024;   // 1024
  int* bsumsC    = bsumsB    + 1024;   // 1024

  const long long base0 = (long long)N * C;   // end of x_out chunk

  const int nbN2 = (N2 + 255) / 256;
  const int nbE  = (E  + 255) / 256;   // <= 1024
  const int nbB  = (EB + 255) / 256;   // <= 1024
  const int nbE8 = (E + 7) / 8;

  hipMemsetAsync(counts, 0, sizeof(int) * 2 * (size_t)G, stream);

  k_count<<<64, 512, 0, stream>>>(batch, N, br_batch, N2,
                                  counts, counts2, dropcnt, brmask, G);

  k_scan<<<1, 512, 0, stream>>>(counts, counts2, edge_num, G,
                                node_off, node_off2, e_off);

  k_score<<<(N * 64 + 255) / 256, 256, 0, stream>>>(x, W, batch, counts, node_off,
                                                    out, low, rem, C, N);

  k_pass1<<<(max(E, N) + 255) / 256, 256, 0, stream>>>(
      edge_index, e_off, node_off, node_off2, counts, batch, low, br_com_num,
      rem, brmask, E, N, G);

  k_pass2<<<nbE + nbN2 + nbB, 256, 0, stream>>>(edge_index, rem, e_off, brmask,
                                                br_index, dropcnt,
                                                bsumsA, bsumsB, bsumsC,
                                                E, N2, EB, G, nbE, nbN2);

  k_scanABC<<<3, 1024, 0, stream>>>(bsumsA, nbE, bsumsB, nbN2, bsumsC, nbB,
                                    totals);

  k_pass3<<<nbE + nbN2, 256, 0, stream>>>(edge_index, rem, bsumsA, bsumsB, totals,
                                          edge_num, dropcnt, brmask,
                                          edge_pos, remap, out, base0,
                                          E, N2, G, DE, nbE);

  k_pass45<<<nbB + nbE8 + (N2 + 1) / 2, 256, 0, stream>>>(
      br_index, remap, bsumsC, totals, edge_inform, edge_pos,
      br_feature, br_batch, out, base0,
      G, DE, C, EB, E, N2, nbB, nbE8);
}